// Round 18
// baseline (873.031 us; speedup 1.0000x reference)
//
#include <hip/hip_runtime.h>
#include <stdint.h>

// ---------------------------------------------------------------------------
// FlatSquare7x7NNUEv4 — round 18: TS=8, 256-thr WG, LDS 40,960 B (80 rows).
// Evidence: 40KB/256-thr WGs reach ~45% occupancy (R11/R12, pool=160KB);
// round 17 stalls at 23% (72KB -> 2 WGs) with no pipe saturated -> latency
// bound. Wave grids are DUPLICATION-FREE NT2 (each wave owns its N-tiles):
// conv1 MT4NT2 + MT1NT2, conv2 MT2NT2 x4blk, conv3 MT2NT2, conv4 MT1NT2
// x4blk -> total B-L2 traffic unchanged vs round 17 despite 2x WGs.
// Numerics IDENTICAL (absmax must stay 0.01757812).
//   A·W ≈ Ah·Wh + 2^-11·(Als·Wh), weights f16 RTN.
// ---------------------------------------------------------------------------

typedef _Float16 f16x8 __attribute__((ext_vector_type(8)));
typedef _Float16 f16x4 __attribute__((ext_vector_type(4)));
typedef float f32x4 __attribute__((ext_vector_type(4)));

// chunk tables: groups: [0..3]=g0, [4..11]=g1, [12..15]=g2
static __device__ __constant__ int CH_Y0[16] = {0,0,3,3, 0,1,3,2, 1,0,2,3, 1,1,2,2};
static __device__ __constant__ int CH_X0[16] = {0,3,3,0, 1,3,2,0, 0,2,3,1, 1,2,2,1};
static __device__ __constant__ int CH_K [16] = {0,1,2,3, 0,1,2,3, 0,1,2,3, 0,1,2,3};
static __device__ __constant__ int CH_T [16] = {0,0,0,0, 0,0,0,0, 1,1,1,1, 0,0,0,0};

#define TS 8

// ---- global weight image (bytes within group) ----
#define G_STRIDE 678912
#define GW1   0
#define GW2   65536
#define GW3   327680
#define GW4   393216
#define GW5   655360
#define GW0   671744
#define GBIAS 675840
#define G_WORDS   167936     // f16 region words per group (656KB/4)
#define G_STRIDE_W 169728    // group stride in words
#define MLP_WORD_OFF 509184
#define FEAT_OFF_BYTES (2*1024*1024)

#define LO_SCALE 2048.0f
#define LO_INV   (1.0f/2048.0f)

__device__ __forceinline__ int base3(int z){ return (z>>1)*3 + (z&1); }
__device__ __forceinline__ int clampi(int v, int lo, int hi) { return v < lo ? lo : (v > hi ? hi : v); }
__device__ __forceinline__ int f0swz(int row){ return (row ^ (row>>2)) & 7; }

__device__ inline float bninv(const float* bn, int g, int C, int c) {
  float ga = bn[(g*4+0)*C + c];
  float va = bn[(g*4+3)*C + c];
  return ga / sqrtf(va + 1e-5f);
}
__device__ inline int q8(float x) { return clampi((int)rintf(x), -128, 127); }

// ---------------------------------------------------------------------------
// prep: unchanged (same weight image; lo-halves unused by conv kernel)
// ---------------------------------------------------------------------------
__global__ void prep_kernel(
    const float* __restrict__ w0, const float* __restrict__ b0,
    const float* __restrict__ w1, const float* __restrict__ b1,
    const float* __restrict__ w2, const float* __restrict__ b2,
    const float* __restrict__ w3, const float* __restrict__ b3,
    const float* __restrict__ w4, const float* __restrict__ b4,
    const float* __restrict__ w5, const float* __restrict__ b5,
    const float* __restrict__ bn1, const float* __restrict__ bn2,
    const float* __restrict__ bn3, const float* __restrict__ bn4,
    const float* __restrict__ bn5,
    const float* __restrict__ vw0, const float* __restrict__ vb0,
    const float* __restrict__ vw1, const float* __restrict__ vb1,
    const float* __restrict__ vw2, const float* __restrict__ vb2,
    float* __restrict__ ws)
{
  int idx = blockIdx.x * blockDim.x + threadIdx.x;
  if (idx < 3*G_WORDS) {
    uint32_t* wsU = (uint32_t*)ws;
    int g = idx / G_WORDS;
    int q = idx - g*G_WORDS;
    int stage, blk = 0, sub;
    if      (q < 16384)  { stage = 1; sub = q; }
    else if (q < 81920)  { stage = 2; blk = (q-16384)>>14; sub = (q-16384)&16383; }
    else if (q < 98304)  { stage = 3; sub = q-81920; }
    else if (q < 163840) { stage = 4; blk = (q-98304)>>14; sub = (q-98304)&16383; }
    else                 { stage = 5; sub = q-163840; }
    int isLo, r;
    if (stage == 5) { isLo = sub>>11; r = sub&2047; }
    else            { isLo = sub>>13; r = sub&8191; }
    int pb = r*4;
    int lb = pb ^ (((pb>>8)&7)<<4);     // inverse of kernel-side weight swizzle
    int oc = lb>>8;
    int k0 = (lb&255)>>1;               // even f16 index; word = (k0, k0+1)
    float inv, v0, v1;
    if (stage == 1) {
      inv = bninv(bn1,g,128,oc);
      v0 = w1[(g*128+oc)*128+k0]; v1 = w1[(g*128+oc)*128+k0+1];
    } else if (stage == 2) {
      inv = bninv(bn2,g,128,oc);
      v0 = w2[((g*128+oc)*128+k0)*4+blk]; v1 = w2[((g*128+oc)*128+k0+1)*4+blk];
    } else if (stage == 3) {
      inv = bninv(bn3,g,128,oc);
      v0 = w3[(g*128+oc)*128+k0]; v1 = w3[(g*128+oc)*128+k0+1];
    } else if (stage == 4) {
      inv = bninv(bn4,g,128,oc);
      v0 = w4[((g*128+oc)*128+k0)*4+blk]; v1 = w4[((g*128+oc)*128+k0+1)*4+blk];
    } else {
      inv = bninv(bn5,g,32,oc);
      v0 = w5[(g*32+oc)*128+k0]; v1 = w5[(g*32+oc)*128+k0+1];
    }
    v0 *= inv; v1 *= inv;
    _Float16 h0 = (_Float16)v0, h1 = (_Float16)v1;
    if (isLo) {
      h0 = (_Float16)((v0 - (float)h0) * LO_SCALE);
      h1 = (_Float16)((v1 - (float)h1) * LO_SCALE);
    }
    union { _Float16 h[2]; uint32_t u; } uu;
    uu.h[0] = h0; uu.h[1] = h1;
    wsU[g*G_STRIDE_W + q] = uu.u;
  } else if (idx < 506880) {            // w0: [k=8][c=128] fp32
    int e = idx - 503808; int g = e>>10; int t2 = e&1023;
    int k = t2>>7, c = t2&127;
    ws[g*G_STRIDE_W + 167936 + t2] = w0[((g*128 + c)*2 + (k>>2))*4 + (k&3)];
  } else if (idx < 509184) {            // folded biases [6][128] fp32
    int e = idx - 506880; int g = e/768; int r = e - g*768;
    int l = r>>7, c = r&127;
    float t;
    if (l == 0) {
      t = b0[g*128 + c];
    } else if (l < 5) {
      const float* bn = (l==1) ? bn1 : (l==2) ? bn2 : (l==3) ? bn3 : bn4;
      const float* bb = (l==1) ? b1  : (l==2) ? b2  : (l==3) ? b3  : b4;
      float inv = bninv(bn, g, 128, c);
      t = (bb[g*128 + c] - bn[(g*4+2)*128 + c]) * inv + bn[(g*4+1)*128 + c];
    } else {
      if (c < 32) {
        float inv = bninv(bn5, g, 32, c);
        t = (b5[g*32 + c] - bn5[(g*4+2)*32 + c]) * inv + bn5[(g*4+1)*32 + c];
      } else t = 0.f;
    }
    ws[g*G_STRIDE_W + 168960 + r] = t;
  } else if (idx < 511395) {            // quantized MLP ints
    int e = idx - MLP_WORD_OFF;
    int* wsI = (int*)ws;
    int val;
    if      (e < 1024) val = q8(vw0[e] * 256.f);
    else if (e < 1056) val = (int)rintf(vb0[e-1024] * 32768.f);
    else if (e < 2080) val = q8(vw1[e-1056] * 128.f);
    else if (e < 2112) val = (int)rintf(vb1[e-2080] * 16384.f);
    else if (e < 2208) val = q8(vw2[e-2112] * 128.f);
    else               val = (int)rintf(vb2[e-2208] * 16384.f);
    wsI[idx] = val;
  }
}

// ---------------------------------------------------------------------------
// fused MFMA conv stack — B (hi only) from global, 40KB LDS, 4 waves, TS=8
// ---------------------------------------------------------------------------
#define MFMA(a,b,c) __builtin_amdgcn_mfma_f32_16x16x32_f16((a),(b),(c),0,0,0)

// MODE 0: contiguous rows, f = f0swz(row).
// MODE 2: conv2 gather from gen1 layout, f=((s&3)<<1)|(w&1), row=9s+w (s<8).
// MODE 4: conv4 gather from gen3 layout, f=rr&7 (row=rr*4+blk).
template<int MT, int NT, int MODE>
__device__ __forceinline__ void phaseF(const char* AHb, const char* ALb,
    const char* __restrict__ gwH,
    int m0, int n0, int lane, int blk, f32x4 acc1[][NT], f32x4 acc2[][NT])
{
  const int l15 = lane & 15, kq = (lane >> 4) & 3;
#pragma unroll
  for (int kb = 0; kb < 4; ++kb) {
    const int ko2 = (kb*32 + kq*8)*2;
    f16x8 Bh_[NT];
#pragma unroll
    for (int n = 0; n < NT; ++n) {
      int brow = (n0+n)*16 + l15;
      int boff = (brow*256 + ko2) ^ ((brow&7)<<4);   // weight image swizzle
      Bh_[n] = *(const f16x8*)(gwH + boff);
    }
#pragma unroll
    for (int m = 0; m < MT; ++m) {
      const int rr = (m0+m)*16 + l15;
      int row, f;
      if (MODE == 0)      { row = rr; f = f0swz(rr); }
      else if (MODE == 2) { int s = rr>>2; int w = base3(rr&3) + base3(blk);
                            row = s*9 + w; f = ((s&3)<<1) | (w&1); }
      else                { row = rr*4 + blk; f = rr & 7; }
      const int aoff = (row*256 + ko2) ^ (f<<4);
      f16x8 Ah = *(const f16x8*)(AHb + aoff);
      f16x8 Al = *(const f16x8*)(ALb + aoff);
#pragma unroll
      for (int n = 0; n < NT; ++n) {
        acc1[m][n] = MFMA(Ah, Bh_[n], acc1[m][n]);
        acc2[m][n] = MFMA(Al, Bh_[n], acc2[m][n]);
      }
    }
  }
}

// GEN 0: f=f0swz(row); GEN 2: f=((s&3)<<1)|(w&1) (s=(row*57)>>9 exact for
// row<144); GEN 4: f=(row>>2)&7.
template<int GEN>
__device__ __forceinline__ void wbvalG(char* ah, char* al, int row, int col, float v) {
  _Float16 h = (_Float16)v;
  _Float16 l = (_Float16)((v - (float)h) * LO_SCALE);
  int f;
  if (GEN == 0)      f = f0swz(row);
  else if (GEN == 2) { int s = (row*57)>>9; int w = row - s*9; f = ((s&3)<<1) | (w&1); }
  else               f = (row >> 2) & 7;
  int sb = (row*256 + col*2) ^ (f<<4);
  *(_Float16*)(ah + sb) = h;
  *(_Float16*)(al + sb) = l;
}

template<int MT, int NT, int GEN>
__device__ __forceinline__ void writeback(char* AHb, char* ALb,
    const float* __restrict__ biasG,
    int layer, int m0, int n0, int lane, f32x4 acc1[][NT], f32x4 acc2[][NT])
{
  const int l15 = lane & 15, rq = (lane >> 4) & 3;
#pragma unroll
  for (int m = 0; m < MT; ++m)
#pragma unroll
    for (int n = 0; n < NT; ++n) {
      int col = (n0+n)*16 + l15;
      float bb = biasG[layer*128 + col];
#pragma unroll
      for (int q = 0; q < 4; ++q) {
        int row = (m0+m)*16 + rq*4 + q;
        float v = acc1[m][n][q] + acc2[m][n][q]*LO_INV + bb;
        v = fmaxf(v, 0.f);
        wbvalG<GEN>(AHb, ALb, row, col, v);
      }
    }
}

__global__ __launch_bounds__(256, 2)
void conv_mfma(
    const float* __restrict__ x, const char* __restrict__ wsb,
    signed char* __restrict__ feat, int B, int wgPerChunk)
{
  __shared__ __align__(16) char ldsbuf[40960];   // Ah[80][128] + Al[80][128]
  char* AHb = ldsbuf;
  char* ALb = ldsbuf + 20480;

  const int tid  = threadIdx.x;
  const int lane = tid & 63;
  const int wave = tid >> 6;            // 0-3

  const int wg = blockIdx.x;
  const int chunkG = wg / wgPerChunk;
  const int b0 = (wg - chunkG*wgPerChunk) * TS;
  const int g = (chunkG < 4) ? 0 : (chunkG < 12) ? 1 : 2;
  const char* gw = wsb + g*G_STRIDE;
  const float* biasG = (const float*)(gw + GBIAS);

  // ---- conv0 fused with input load: __shfl allgather, 1 sample/32-thread,
  //      packed f16x4 b64 writeback ----
  {
    const int s = tid >> 5, u = tid & 31;   // s in 0..7
    const int ic = u >> 4, pos = u & 15;
    const int i = pos >> 2, j2 = pos & 3;
    int tt = CH_T[chunkG], kk = CH_K[chunkG];
    int a = tt ? j2 : i, bb2 = tt ? i : j2;
    int py, px;
    if      (kk == 0) { py = a;     px = bb2;   }
    else if (kk == 1) { py = bb2;   px = 3-a;   }
    else if (kk == 2) { py = 3-a;   px = 3-bb2; }
    else              { py = 3-bb2; px = a;     }
    int sy = CH_Y0[chunkG] + py, sx = CH_X0[chunkG] + px;
    const float* w0s = (const float*)(gw + GW0);
    float4 wr[8];
#pragma unroll
    for (int k = 0; k < 8; ++k) wr[k] = ((const float4*)(w0s + k*128))[u];
    float4 bb4 = ((const float4*)biasG)[u];
    float bbv[4] = {bb4.x, bb4.y, bb4.z, bb4.w};
    const int gbase = lane & 32;
    float xval = x[((b0+s)*2 + ic)*49 + sy*7 + sx];
    float xv[32];
#pragma unroll
    for (int t2 = 0; t2 < 32; ++t2) xv[t2] = __shfl(xval, gbase | t2, 64);
#pragma unroll
    for (int oy = 0; oy < 3; ++oy)
#pragma unroll
      for (int ox = 0; ox < 3; ++ox) {
        float accv[4];
#pragma unroll
        for (int q = 0; q < 4; ++q) accv[q] = bbv[q];
#pragma unroll
        for (int ic2 = 0; ic2 < 2; ++ic2)
#pragma unroll
          for (int dy = 0; dy < 2; ++dy)
#pragma unroll
            for (int dx = 0; dx < 2; ++dx) {
              float xvv = xv[ic2*16 + (oy+dy)*4 + ox+dx];
              int k = ic2*4 + dy*2 + dx;
              accv[0] = fmaf(xvv, wr[k].x, accv[0]);
              accv[1] = fmaf(xvv, wr[k].y, accv[1]);
              accv[2] = fmaf(xvv, wr[k].z, accv[2]);
              accv[3] = fmaf(xvv, wr[k].w, accv[3]);
            }
        int row = s*9 + oy*3 + ox;
        f16x4 hv, lv;
#pragma unroll
        for (int q = 0; q < 4; ++q) {
          float v = fmaxf(accv[q], 0.f);
          _Float16 h = (_Float16)v;
          hv[q] = h;
          lv[q] = (_Float16)((v - (float)h) * LO_SCALE);
        }
        int sb = (row*256 + u*8) ^ (f0swz(row)<<4);
        *(f16x4*)(AHb + sb) = hv;
        *(f16x4*)(ALb + sb) = lv;
      }
  }
  __syncthreads();                              // gen0 ready (72 rows valid)

  // ---- conv1: pass a MT4NT2 (rows 0-63), pass b MT1NT2 (rows 64-79);
  //      dup-free: wave owns n-tiles 2w,2w+1 ----
  {
    {
      f32x4 a1[4][2] = {}; f32x4 a2[4][2] = {};
      phaseF<4,2,0>(AHb, ALb, gw+GW1, 0, wave*2, lane, 0, a1, a2);
      __syncthreads();                          // all reads of rows 0-63 done
      writeback<4,2,2>(AHb, ALb, biasG, 1, 0, wave*2, lane, a1, a2);
    }
    {
      // reads rows 64-79 — disjoint from pass-a WB rows 0-63
      f32x4 a1[1][2] = {}; f32x4 a2[1][2] = {};
      phaseF<1,2,0>(AHb, ALb, gw+GW1, 4, wave*2, lane, 0, a1, a2);
      __syncthreads();                          // reads 64-79 + WB-a done
      writeback<1,2,2>(AHb, ALb, biasG, 1, 4, wave*2, lane, a1, a2);
    }
  }
  __syncthreads();                              // gen1 complete

  // ---- conv2: gathers gen1 (MODE 2), 4 blocks barrier-free, MT2NT2 ----
  {
    f32x4 a1[2][2] = {}; f32x4 a2[2][2] = {};
#pragma unroll
    for (int blk = 0; blk < 4; ++blk)
      phaseF<2,2,2>(AHb, ALb, gw+GW2+blk*65536, 0, wave*2, lane, blk, a1, a2);
    __syncthreads();                            // all conv2 reads done
    writeback<2,2,0>(AHb, ALb, biasG, 2, 0, wave*2, lane, a1, a2);
  }
  __syncthreads();                              // gen2 ready (32 rows)

  // ---- conv3: reads gen2 (MODE 0), writes gen3 (GEN 4), MT2NT2 ----
  {
    f32x4 a1[2][2] = {}; f32x4 a2[2][2] = {};
    phaseF<2,2,0>(AHb, ALb, gw+GW3, 0, wave*2, lane, 0, a1, a2);
    __syncthreads();                            // conv3 reads done
    writeback<2,2,4>(AHb, ALb, biasG, 3, 0, wave*2, lane, a1, a2);
  }
  __syncthreads();                              // gen3 ready (32 rows)

  // ---- conv4: gathers gen3 (MODE 4), 4 blocks barrier-free, MT1NT2 ----
  //      (rr>=8 reads stale rows 32-63: garbage-in, rows 8-15 out never used)
  {
    f32x4 a1[1][2] = {}; f32x4 a2[1][2] = {};
#pragma unroll
    for (int blk = 0; blk < 4; ++blk)
      phaseF<1,2,4>(AHb, ALb, gw+GW4+blk*65536, 0, wave*2, lane, blk, a1, a2);
    __syncthreads();                            // conv4 reads done
    writeback<1,2,0>(AHb, ALb, biasG, 4, 0, wave*2, lane, a1, a2);
  }
  __syncthreads();                              // gen4 ready (8 rows valid)

  // ---- conv5: reads gen4 (MODE 0), quantize features (waves 0,1 only) ----
  if (wave < 2) {
    f32x4 a1[1][1] = {}; f32x4 a2[1][1] = {};
    phaseF<1,1,0>(AHb, ALb, gw+GW5, 0, wave, lane, 0, a1, a2);
    int c = wave*16 + (lane & 15);
    float bb = biasG[5*128 + c];
#pragma unroll
    for (int q = 0; q < 4; ++q) {
      int s = ((lane >> 4) & 3)*4 + q;          // 0-15; only 0-7 real
      if (s < TS) {
        float f = a1[0][0][q] + a2[0][0][q]*LO_INV + bb;
        f = fminf(fmaxf(f, -1.0f), 127.0f/128.0f);
        int qi = clampi((int)rintf(f * 128.0f), -128, 127);
        feat[((long)chunkG*B + b0 + s)*32 + c] = (signed char)qi;
      }
    }
  }
}

// ---------------------------------------------------------------------------
// value MLP: exact integer arithmetic (unchanged, verified round 1)
// ---------------------------------------------------------------------------
__global__ __launch_bounds__(256) void mlp_kernel(
    const signed char* __restrict__ feat,
    const int* __restrict__ mw,
    float* __restrict__ out, int B)
{
  int b = blockIdx.x * blockDim.x + threadIdx.x;
  if (b >= B) return;
  int S[32];
#pragma unroll
  for (int c = 0; c < 32; ++c) S[c] = 0;
  for (int ch = 0; ch < 16; ++ch) {
    const signed char* f = feat + ((long)ch*B + b)*32;
#pragma unroll
    for (int c = 0; c < 32; ++c) S[c] += f[c];
  }
  int x1[32];
#pragma unroll
  for (int c = 0; c < 32; ++c) x1[c] = clampi(S[c], -128, 127);

  const int* wq0 = mw;        const int* bq0 = mw + 1024;
  const int* wq1 = mw + 1056; const int* bq1 = mw + 2080;
  const int* wq2 = mw + 2112; const int* bq2 = mw + 2208;

  int x2[32];
#pragma unroll
  for (int o = 0; o < 32; ++o) {
    int acc = bq0[o];
    for (int i = 0; i < 32; ++i) acc += x1[i] * wq0[o*32 + i];
    acc = clampi(acc, 0, 32512);
    int r = acc >> 8, fr = acc & 255;
    r += (fr > 128 || (fr == 128 && (r & 1))) ? 1 : 0;
    x2[o] = r;
  }
  int x3[32];
#pragma unroll
  for (int o = 0; o < 32; ++o) {
    int acc = bq1[o];
    for (int i = 0; i < 32; ++i) acc += x2[i] * wq1[o*32 + i];
    acc = clampi(acc, 0, 16256);
    int r = acc >> 7, fr = acc & 127;
    r += (fr > 64 || (fr == 64 && (r & 1))) ? 1 : 0;
    x3[o] = r;
  }
  for (int o = 0; o < 3; ++o) {
    int acc = bq2[o];
    for (int i = 0; i < 32; ++i) acc += x3[i] * wq2[o*32 + i];
    out[b*3 + o] = (float)acc / 16384.0f;
  }
}

__global__ void zero_kernel(float4* __restrict__ p, int n4) {
  int i = blockIdx.x * blockDim.x + threadIdx.x;
  if (i < n4) p[i] = make_float4(0.f, 0.f, 0.f, 0.f);
}

// ---------------------------------------------------------------------------
extern "C" void kernel_launch(void* const* d_in, const int* in_sizes, int n_in,
                              void* d_out, int out_size, void* d_ws, size_t ws_size,
                              hipStream_t stream)
{
  const float* x   = (const float*)d_in[0];
  const float* w0  = (const float*)d_in[1];
  const float* b0  = (const float*)d_in[2];
  const float* w1  = (const float*)d_in[3];
  const float* b1  = (const float*)d_in[4];
  const float* w2  = (const float*)d_in[5];
  const float* b2  = (const float*)d_in[6];
  const float* w3  = (const float*)d_in[7];
  const float* b3  = (const float*)d_in[8];
  const float* w4  = (const float*)d_in[9];
  const float* b4  = (const float*)d_in[10];
  const float* w5  = (const float*)d_in[11];
  const float* b5  = (const float*)d_in[12];
  const float* bn1 = (const float*)d_in[13];
  const float* bn2 = (const float*)d_in[14];
  const float* bn3 = (const float*)d_in[15];
  const float* bn4 = (const float*)d_in[16];
  const float* bn5 = (const float*)d_in[17];
  const float* vw0 = (const float*)d_in[18];
  const float* vb0 = (const float*)d_in[19];
  const float* vw1 = (const float*)d_in[20];
  const float* vb1 = (const float*)d_in[21];
  const float* vw2 = (const float*)d_in[22];
  const float* vb2 = (const float*)d_in[23];

  const int B = in_sizes[0] / 98;
  float* ws = (float*)d_ws;
  signed char* feat = (signed char*)d_ws + FEAT_OFF_BYTES;
  float* out = (float*)d_out;

  prep_kernel<<<(511395 + 255)/256, 256, 0, stream>>>(
      w0,b0,w1,b1,w2,b2,w3,b3,w4,b4,w5,b5,
      bn1,bn2,bn3,bn4,bn5, vw0,vb0,vw1,vb1,vw2,vb2, ws);

  const int wgPerChunk = B / TS;
  conv_mfma<<<16*wgPerChunk, 256, 0, stream>>>(
      x, (const char*)d_ws, feat, B, wgPerChunk);

  mlp_kernel<<<(B + 255)/256, 256, 0, stream>>>(feat, (const int*)d_ws + MLP_WORD_OFF, out, B);

  {
    int n4 = B*49/4;
    zero_kernel<<<(n4 + 255)/256, 256, 0, stream>>>((float4*)(out + 3*B), n4);
  }
}

// Round 19
// 750.182 us; speedup vs baseline: 1.1638x; 1.1638x over previous
//
#include <hip/hip_runtime.h>
#include <stdint.h>

// ---------------------------------------------------------------------------
// FlatSquare7x7NNUEv4 — round 19: round-17 structure (best: 752us) restored
// exactly, plus s_setprio(1) around MFMA clusters. R17 runs 2 independent
// WGs/CU (phase-skewed barrier domains) -> setprio's wave-role-diversity
// regime; MFMA-entering waves preempt the other WG's load/VALU waves.
// R18's occupancy fork (44% occ) regressed: A-row dup x2 + conflicts x1.7.
// Numerics IDENTICAL (absmax must stay 0.01757812).
//   A·W ≈ Ah·Wh + 2^-11·(Als·Wh), weights f16 RTN.
// ---------------------------------------------------------------------------

typedef _Float16 f16x8 __attribute__((ext_vector_type(8)));
typedef _Float16 f16x4 __attribute__((ext_vector_type(4)));
typedef float f32x4 __attribute__((ext_vector_type(4)));

// chunk tables: groups: [0..3]=g0, [4..11]=g1, [12..15]=g2
static __device__ __constant__ int CH_Y0[16] = {0,0,3,3, 0,1,3,2, 1,0,2,3, 1,1,2,2};
static __device__ __constant__ int CH_X0[16] = {0,3,3,0, 1,3,2,0, 0,2,3,1, 1,2,2,1};
static __device__ __constant__ int CH_K [16] = {0,1,2,3, 0,1,2,3, 0,1,2,3, 0,1,2,3};
static __device__ __constant__ int CH_T [16] = {0,0,0,0, 0,0,0,0, 1,1,1,1, 0,0,0,0};

// ---- global weight image (bytes within group) ----
#define G_STRIDE 678912
#define GW1   0
#define GW2   65536
#define GW3   327680
#define GW4   393216
#define GW5   655360
#define GW0   671744
#define GBIAS 675840
#define G_WORDS   167936     // f16 region words per group (656KB/4)
#define G_STRIDE_W 169728    // group stride in words
#define MLP_WORD_OFF 509184
#define FEAT_OFF_BYTES (2*1024*1024)

#define LO_SCALE 2048.0f
#define LO_INV   (1.0f/2048.0f)

__device__ __forceinline__ int base3(int z){ return (z>>1)*3 + (z&1); }
__device__ __forceinline__ int clampi(int v, int lo, int hi) { return v < lo ? lo : (v > hi ? hi : v); }
__device__ __forceinline__ int f0swz(int row){ return (row ^ (row>>2)) & 7; }

__device__ inline float bninv(const float* bn, int g, int C, int c) {
  float ga = bn[(g*4+0)*C + c];
  float va = bn[(g*4+3)*C + c];
  return ga / sqrtf(va + 1e-5f);
}
__device__ inline int q8(float x) { return clampi((int)rintf(x), -128, 127); }

// ---------------------------------------------------------------------------
// prep: unchanged (same weight image; lo-halves unused by conv kernel)
// ---------------------------------------------------------------------------
__global__ void prep_kernel(
    const float* __restrict__ w0, const float* __restrict__ b0,
    const float* __restrict__ w1, const float* __restrict__ b1,
    const float* __restrict__ w2, const float* __restrict__ b2,
    const float* __restrict__ w3, const float* __restrict__ b3,
    const float* __restrict__ w4, const float* __restrict__ b4,
    const float* __restrict__ w5, const float* __restrict__ b5,
    const float* __restrict__ bn1, const float* __restrict__ bn2,
    const float* __restrict__ bn3, const float* __restrict__ bn4,
    const float* __restrict__ bn5,
    const float* __restrict__ vw0, const float* __restrict__ vb0,
    const float* __restrict__ vw1, const float* __restrict__ vb1,
    const float* __restrict__ vw2, const float* __restrict__ vb2,
    float* __restrict__ ws)
{
  int idx = blockIdx.x * blockDim.x + threadIdx.x;
  if (idx < 3*G_WORDS) {
    uint32_t* wsU = (uint32_t*)ws;
    int g = idx / G_WORDS;
    int q = idx - g*G_WORDS;
    int stage, blk = 0, sub;
    if      (q < 16384)  { stage = 1; sub = q; }
    else if (q < 81920)  { stage = 2; blk = (q-16384)>>14; sub = (q-16384)&16383; }
    else if (q < 98304)  { stage = 3; sub = q-81920; }
    else if (q < 163840) { stage = 4; blk = (q-98304)>>14; sub = (q-98304)&16383; }
    else                 { stage = 5; sub = q-163840; }
    int isLo, r;
    if (stage == 5) { isLo = sub>>11; r = sub&2047; }
    else            { isLo = sub>>13; r = sub&8191; }
    int pb = r*4;
    int lb = pb ^ (((pb>>8)&7)<<4);     // inverse of kernel-side weight swizzle
    int oc = lb>>8;
    int k0 = (lb&255)>>1;               // even f16 index; word = (k0, k0+1)
    float inv, v0, v1;
    if (stage == 1) {
      inv = bninv(bn1,g,128,oc);
      v0 = w1[(g*128+oc)*128+k0]; v1 = w1[(g*128+oc)*128+k0+1];
    } else if (stage == 2) {
      inv = bninv(bn2,g,128,oc);
      v0 = w2[((g*128+oc)*128+k0)*4+blk]; v1 = w2[((g*128+oc)*128+k0+1)*4+blk];
    } else if (stage == 3) {
      inv = bninv(bn3,g,128,oc);
      v0 = w3[(g*128+oc)*128+k0]; v1 = w3[(g*128+oc)*128+k0+1];
    } else if (stage == 4) {
      inv = bninv(bn4,g,128,oc);
      v0 = w4[((g*128+oc)*128+k0)*4+blk]; v1 = w4[((g*128+oc)*128+k0+1)*4+blk];
    } else {
      inv = bninv(bn5,g,32,oc);
      v0 = w5[(g*32+oc)*128+k0]; v1 = w5[(g*32+oc)*128+k0+1];
    }
    v0 *= inv; v1 *= inv;
    _Float16 h0 = (_Float16)v0, h1 = (_Float16)v1;
    if (isLo) {
      h0 = (_Float16)((v0 - (float)h0) * LO_SCALE);
      h1 = (_Float16)((v1 - (float)h1) * LO_SCALE);
    }
    union { _Float16 h[2]; uint32_t u; } uu;
    uu.h[0] = h0; uu.h[1] = h1;
    wsU[g*G_STRIDE_W + q] = uu.u;
  } else if (idx < 506880) {            // w0: [k=8][c=128] fp32
    int e = idx - 503808; int g = e>>10; int t2 = e&1023;
    int k = t2>>7, c = t2&127;
    ws[g*G_STRIDE_W + 167936 + t2] = w0[((g*128 + c)*2 + (k>>2))*4 + (k&3)];
  } else if (idx < 509184) {            // folded biases [6][128] fp32
    int e = idx - 506880; int g = e/768; int r = e - g*768;
    int l = r>>7, c = r&127;
    float t;
    if (l == 0) {
      t = b0[g*128 + c];
    } else if (l < 5) {
      const float* bn = (l==1) ? bn1 : (l==2) ? bn2 : (l==3) ? bn3 : bn4;
      const float* bb = (l==1) ? b1  : (l==2) ? b2  : (l==3) ? b3  : b4;
      float inv = bninv(bn, g, 128, c);
      t = (bb[g*128 + c] - bn[(g*4+2)*128 + c]) * inv + bn[(g*4+1)*128 + c];
    } else {
      if (c < 32) {
        float inv = bninv(bn5, g, 32, c);
        t = (b5[g*32 + c] - bn5[(g*4+2)*32 + c]) * inv + bn5[(g*4+1)*32 + c];
      } else t = 0.f;
    }
    ws[g*G_STRIDE_W + 168960 + r] = t;
  } else if (idx < 511395) {            // quantized MLP ints
    int e = idx - MLP_WORD_OFF;
    int* wsI = (int*)ws;
    int val;
    if      (e < 1024) val = q8(vw0[e] * 256.f);
    else if (e < 1056) val = (int)rintf(vb0[e-1024] * 32768.f);
    else if (e < 2080) val = q8(vw1[e-1056] * 128.f);
    else if (e < 2112) val = (int)rintf(vb1[e-2080] * 16384.f);
    else if (e < 2208) val = q8(vw2[e-2112] * 128.f);
    else               val = (int)rintf(vb2[e-2208] * 16384.f);
    wsI[idx] = val;
  }
}

// ---------------------------------------------------------------------------
// fused MFMA conv stack — B (hi only) from global, 72KB LDS, 4 waves, TS=16
// ---------------------------------------------------------------------------
#define MFMA(a,b,c) __builtin_amdgcn_mfma_f32_16x16x32_f16((a),(b),(c),0,0,0)

// MODE 0: contiguous rows, f = f0swz(row).
// MODE 2: conv2 gather from gen1 layout, f=((s&3)<<1)|(w&1), row=9s+w.
// MODE 4: conv4 gather from gen3 layout, f=rr&7 (row=rr*4+blk).
template<int MT, int NT, int MODE>
__device__ __forceinline__ void phaseF(const char* AHb, const char* ALb,
    const char* __restrict__ gwH,
    int m0, int n0, int lane, int blk, f32x4 acc1[][NT], f32x4 acc2[][NT])
{
  const int l15 = lane & 15, kq = (lane >> 4) & 3;
#pragma unroll
  for (int kb = 0; kb < 4; ++kb) {
    const int ko2 = (kb*32 + kq*8)*2;
    f16x8 Bh_[NT];
#pragma unroll
    for (int n = 0; n < NT; ++n) {
      int brow = (n0+n)*16 + l15;
      int boff = (brow*256 + ko2) ^ ((brow&7)<<4);   // weight image swizzle
      Bh_[n] = *(const f16x8*)(gwH + boff);
    }
#pragma unroll
    for (int m = 0; m < MT; ++m) {
      const int rr = (m0+m)*16 + l15;
      int row, f;
      if (MODE == 0)      { row = rr; f = f0swz(rr); }
      else if (MODE == 2) { int s = rr>>2; int w = base3(rr&3) + base3(blk);
                            row = s*9 + w; f = ((s&3)<<1) | (w&1); }
      else                { row = rr*4 + blk; f = rr & 7; }
      const int aoff = (row*256 + ko2) ^ (f<<4);
      f16x8 Ah = *(const f16x8*)(AHb + aoff);
      f16x8 Al = *(const f16x8*)(ALb + aoff);
      __builtin_amdgcn_s_setprio(1);
#pragma unroll
      for (int n = 0; n < NT; ++n) {
        acc1[m][n] = MFMA(Ah, Bh_[n], acc1[m][n]);
        acc2[m][n] = MFMA(Al, Bh_[n], acc2[m][n]);
      }
      __builtin_amdgcn_s_setprio(0);
    }
  }
}

// GEN 0: f=f0swz(row); GEN 2: f=((s&3)<<1)|(w&1) (s=(row*57)>>9 exact for
// row<144); GEN 4: f=(row>>2)&7.
template<int GEN>
__device__ __forceinline__ void wbvalG(char* ah, char* al, int row, int col, float v) {
  _Float16 h = (_Float16)v;
  _Float16 l = (_Float16)((v - (float)h) * LO_SCALE);
  int f;
  if (GEN == 0)      f = f0swz(row);
  else if (GEN == 2) { int s = (row*57)>>9; int w = row - s*9; f = ((s&3)<<1) | (w&1); }
  else               f = (row >> 2) & 7;
  int sb = (row*256 + col*2) ^ (f<<4);
  *(_Float16*)(ah + sb) = h;
  *(_Float16*)(al + sb) = l;
}

template<int MT, int NT, int GEN>
__device__ __forceinline__ void writeback(char* AHb, char* ALb,
    const float* __restrict__ biasG,
    int layer, int m0, int n0, int lane, f32x4 acc1[][NT], f32x4 acc2[][NT])
{
  const int l15 = lane & 15, rq = (lane >> 4) & 3;
#pragma unroll
  for (int m = 0; m < MT; ++m)
#pragma unroll
    for (int n = 0; n < NT; ++n) {
      int col = (n0+n)*16 + l15;
      float bb = biasG[layer*128 + col];
#pragma unroll
      for (int q = 0; q < 4; ++q) {
        int row = (m0+m)*16 + rq*4 + q;
        float v = acc1[m][n][q] + acc2[m][n][q]*LO_INV + bb;
        v = fmaxf(v, 0.f);
        wbvalG<GEN>(AHb, ALb, row, col, v);
      }
    }
}

__global__ __launch_bounds__(256, 2)
void conv_mfma(
    const float* __restrict__ x, const char* __restrict__ wsb,
    signed char* __restrict__ feat, int B, int wgPerChunk)
{
  __shared__ __align__(16) char ldsbuf[73728];   // 72KB: Ah[144][128]+Al
  char* AHb = ldsbuf;
  char* ALb = ldsbuf + 36864;

  const int tid  = threadIdx.x;
  const int lane = tid & 63;
  const int wave = tid >> 6;            // 0-3

  const int wg = blockIdx.x;
  const int chunkG = wg / wgPerChunk;
  const int b0 = (wg - chunkG*wgPerChunk) * 16;
  const int g = (chunkG < 4) ? 0 : (chunkG < 12) ? 1 : 2;
  const char* gw = wsb + g*G_STRIDE;
  const float* biasG = (const float*)(gw + GBIAS);

  // ---- conv0 fused with input load: __shfl allgather, 2 samples/thread,
  //      packed f16x4 b64 writeback (4ch contiguous, same 16B swizzle block)
  {
    const int s0 = tid >> 5, u = tid & 31;
    const int ic = u >> 4, pos = u & 15;
    const int i = pos >> 2, j2 = pos & 3;
    int tt = CH_T[chunkG], kk = CH_K[chunkG];
    int a = tt ? j2 : i, bb2 = tt ? i : j2;
    int py, px;
    if      (kk == 0) { py = a;     px = bb2;   }
    else if (kk == 1) { py = bb2;   px = 3-a;   }
    else if (kk == 2) { py = 3-a;   px = 3-bb2; }
    else              { py = 3-bb2; px = a;     }
    int sy = CH_Y0[chunkG] + py, sx = CH_X0[chunkG] + px;
    const float* w0s = (const float*)(gw + GW0);
    float4 wr[8];
#pragma unroll
    for (int k = 0; k < 8; ++k) wr[k] = ((const float4*)(w0s + k*128))[u];
    float4 bb4 = ((const float4*)biasG)[u];
    float bbv[4] = {bb4.x, bb4.y, bb4.z, bb4.w};
    const int gbase = lane & 32;
#pragma unroll
    for (int p = 0; p < 2; ++p) {
      int sp = s0 + p*8;                // 0..15
      float xval = x[((b0+sp)*2 + ic)*49 + sy*7 + sx];
      float xv[32];
#pragma unroll
      for (int t2 = 0; t2 < 32; ++t2) xv[t2] = __shfl(xval, gbase | t2, 64);
#pragma unroll
      for (int oy = 0; oy < 3; ++oy)
#pragma unroll
        for (int ox = 0; ox < 3; ++ox) {
          float accv[4];
#pragma unroll
          for (int q = 0; q < 4; ++q) accv[q] = bbv[q];
#pragma unroll
          for (int ic2 = 0; ic2 < 2; ++ic2)
#pragma unroll
            for (int dy = 0; dy < 2; ++dy)
#pragma unroll
              for (int dx = 0; dx < 2; ++dx) {
                float xvv = xv[ic2*16 + (oy+dy)*4 + ox+dx];
                int k = ic2*4 + dy*2 + dx;
                accv[0] = fmaf(xvv, wr[k].x, accv[0]);
                accv[1] = fmaf(xvv, wr[k].y, accv[1]);
                accv[2] = fmaf(xvv, wr[k].z, accv[2]);
                accv[3] = fmaf(xvv, wr[k].w, accv[3]);
              }
          int row = sp*9 + oy*3 + ox;
          f16x4 hv, lv;
#pragma unroll
          for (int q = 0; q < 4; ++q) {
            float v = fmaxf(accv[q], 0.f);
            _Float16 h = (_Float16)v;
            hv[q] = h;
            lv[q] = (_Float16)((v - (float)h) * LO_SCALE);
          }
          int sb = (row*256 + u*8) ^ (f0swz(row)<<4);
          *(f16x4*)(AHb + sb) = hv;
          *(f16x4*)(ALb + sb) = lv;
        }
    }
  }
  __syncthreads();                              // BAR B: gen0 ready (144 rows)

  // ---- conv1: 3 passes MT2NT4 (rows 0-63), MT2NT4 (64-127), MT1NT2 (128-143)
  //      with read||writeback overlap (disjoint row ranges)
  {
    {
      f32x4 a1[2][4] = {}; f32x4 a2[2][4] = {};
      phaseF<2,4,0>(AHb, ALb, gw+GW1, (wave>>1)*2, (wave&1)*4, lane, 0, a1, a2);
      __syncthreads();                          // all reads of rows 0-63 done
      writeback<2,4,2>(AHb, ALb, biasG, 1, (wave>>1)*2, (wave&1)*4, lane, a1, a2);
    }
    {
      // reads rows 64-127 — disjoint from pass-a WB rows 0-63
      f32x4 a1[2][4] = {}; f32x4 a2[2][4] = {};
      phaseF<2,4,0>(AHb, ALb, gw+GW1, 4+(wave>>1)*2, (wave&1)*4, lane, 0, a1, a2);
      __syncthreads();                          // reads 64-127 + WB-a done
      writeback<2,4,2>(AHb, ALb, biasG, 1, 4+(wave>>1)*2, (wave&1)*4, lane, a1, a2);
    }
    {
      // reads rows 128-143 — disjoint from pass-b WB rows 64-127
      f32x4 a1[1][2] = {}; f32x4 a2[1][2] = {};
      phaseF<1,2,0>(AHb, ALb, gw+GW1, 8, wave*2, lane, 0, a1, a2);
      __syncthreads();                          // reads 128-143 + WB-b done
      writeback<1,2,2>(AHb, ALb, biasG, 1, 8, wave*2, lane, a1, a2);
    }
  }
  __syncthreads();                              // BAR E: gen1 complete

  // ---- conv2: gathers gen1 (MODE 2), 4 blocks barrier-free, MT2NT4 ----
  {
    f32x4 a1[2][4] = {}; f32x4 a2[2][4] = {};
#pragma unroll
    for (int blk = 0; blk < 4; ++blk)
      phaseF<2,4,2>(AHb, ALb, gw+GW2+blk*65536,
                    (wave>>1)*2, (wave&1)*4, lane, blk, a1, a2);
    __syncthreads();                            // BAR F: all conv2 reads done
    writeback<2,4,0>(AHb, ALb, biasG, 2, (wave>>1)*2, (wave&1)*4, lane, a1, a2);
  }
  __syncthreads();                              // BAR G: gen2 ready

  // ---- conv3: reads gen2 (MODE 0), writes gen3 (GEN 4), MT2NT4 ----
  {
    f32x4 a1[2][4] = {}; f32x4 a2[2][4] = {};
    phaseF<2,4,0>(AHb, ALb, gw+GW3, (wave>>1)*2, (wave&1)*4, lane, 0, a1, a2);
    __syncthreads();                            // BAR H: conv3 reads done
    writeback<2,4,4>(AHb, ALb, biasG, 3, (wave>>1)*2, (wave&1)*4, lane, a1, a2);
  }
  __syncthreads();                              // BAR I: gen3 ready

  // ---- conv4: gathers gen3 (MODE 4), 4 blocks barrier-free, MT1NT2 ----
  {
    f32x4 a1[1][2] = {}; f32x4 a2[1][2] = {};
#pragma unroll
    for (int blk = 0; blk < 4; ++blk)
      phaseF<1,2,4>(AHb, ALb, gw+GW4+blk*65536,
                    0, wave*2, lane, blk, a1, a2);
    __syncthreads();                            // BAR J: conv4 reads done
    writeback<1,2,0>(AHb, ALb, biasG, 4, 0, wave*2, lane, a1, a2);
  }
  __syncthreads();                              // BAR K: gen4 ready

  // ---- conv5: reads gen4 (MODE 0), quantize features (waves 0,1 only) ----
  if (wave < 2) {
    f32x4 a1[1][1] = {}; f32x4 a2[1][1] = {};
    phaseF<1,1,0>(AHb, ALb, gw+GW5, 0, wave, lane, 0, a1, a2);
    int c = wave*16 + (lane & 15);
    float bb = biasG[5*128 + c];
#pragma unroll
    for (int q = 0; q < 4; ++q) {
      int s = ((lane >> 4) & 3)*4 + q;
      float f = a1[0][0][q] + a2[0][0][q]*LO_INV + bb;
      f = fminf(fmaxf(f, -1.0f), 127.0f/128.0f);
      int qi = clampi((int)rintf(f * 128.0f), -128, 127);
      feat[((long)chunkG*B + b0 + s)*32 + c] = (signed char)qi;
    }
  }
}

// ---------------------------------------------------------------------------
// value MLP: exact integer arithmetic (unchanged, verified round 1)
// ---------------------------------------------------------------------------
__global__ __launch_bounds__(256) void mlp_kernel(
    const signed char* __restrict__ feat,
    const int* __restrict__ mw,
    float* __restrict__ out, int B)
{
  int b = blockIdx.x * blockDim.x + threadIdx.x;
  if (b >= B) return;
  int S[32];
#pragma unroll
  for (int c = 0; c < 32; ++c) S[c] = 0;
  for (int ch = 0; ch < 16; ++ch) {
    const signed char* f = feat + ((long)ch*B + b)*32;
#pragma unroll
    for (int c = 0; c < 32; ++c) S[c] += f[c];
  }
  int x1[32];
#pragma unroll
  for (int c = 0; c < 32; ++c) x1[c] = clampi(S[c], -128, 127);

  const int* wq0 = mw;        const int* bq0 = mw + 1024;
  const int* wq1 = mw + 1056; const int* bq1 = mw + 2080;
  const int* wq2 = mw + 2112; const int* bq2 = mw + 2208;

  int x2[32];
#pragma unroll
  for (int o = 0; o < 32; ++o) {
    int acc = bq0[o];
    for (int i = 0; i < 32; ++i) acc += x1[i] * wq0[o*32 + i];
    acc = clampi(acc, 0, 32512);
    int r = acc >> 8, fr = acc & 255;
    r += (fr > 128 || (fr == 128 && (r & 1))) ? 1 : 0;
    x2[o] = r;
  }
  int x3[32];
#pragma unroll
  for (int o = 0; o < 32; ++o) {
    int acc = bq1[o];
    for (int i = 0; i < 32; ++i) acc += x2[i] * wq1[o*32 + i];
    acc = clampi(acc, 0, 16256);
    int r = acc >> 7, fr = acc & 127;
    r += (fr > 64 || (fr == 64 && (r & 1))) ? 1 : 0;
    x3[o] = r;
  }
  for (int o = 0; o < 3; ++o) {
    int acc = bq2[o];
    for (int i = 0; i < 32; ++i) acc += x3[i] * wq2[o*32 + i];
    out[b*3 + o] = (float)acc / 16384.0f;
  }
}

__global__ void zero_kernel(float4* __restrict__ p, int n4) {
  int i = blockIdx.x * blockDim.x + threadIdx.x;
  if (i < n4) p[i] = make_float4(0.f, 0.f, 0.f, 0.f);
}

// ---------------------------------------------------------------------------
extern "C" void kernel_launch(void* const* d_in, const int* in_sizes, int n_in,
                              void* d_out, int out_size, void* d_ws, size_t ws_size,
                              hipStream_t stream)
{
  const float* x   = (const float*)d_in[0];
  const float* w0  = (const float*)d_in[1];
  const float* b0  = (const float*)d_in[2];
  const float* w1  = (const float*)d_in[3];
  const float* b1  = (const float*)d_in[4];
  const float* w2  = (const float*)d_in[5];
  const float* b2  = (const float*)d_in[6];
  const float* w3  = (const float*)d_in[7];
  const float* b3  = (const float*)d_in[8];
  const float* w4  = (const float*)d_in[9];
  const float* b4  = (const float*)d_in[10];
  const float* w5  = (const float*)d_in[11];
  const float* b5  = (const float*)d_in[12];
  const float* bn1 = (const float*)d_in[13];
  const float* bn2 = (const float*)d_in[14];
  const float* bn3 = (const float*)d_in[15];
  const float* bn4 = (const float*)d_in[16];
  const float* bn5 = (const float*)d_in[17];
  const float* vw0 = (const float*)d_in[18];
  const float* vb0 = (const float*)d_in[19];
  const float* vw1 = (const float*)d_in[20];
  const float* vb1 = (const float*)d_in[21];
  const float* vw2 = (const float*)d_in[22];
  const float* vb2 = (const float*)d_in[23];

  const int B = in_sizes[0] / 98;
  float* ws = (float*)d_ws;
  signed char* feat = (signed char*)d_ws + FEAT_OFF_BYTES;
  float* out = (float*)d_out;

  prep_kernel<<<(511395 + 255)/256, 256, 0, stream>>>(
      w0,b0,w1,b1,w2,b2,w3,b3,w4,b4,w5,b5,
      bn1,bn2,bn3,bn4,bn5, vw0,vb0,vw1,vb1,vw2,vb2, ws);

  conv_mfma<<<B, 256, 0, stream>>>(
      x, (const char*)d_ws, feat, B, B/16);

  mlp_kernel<<<(B + 255)/256, 256, 0, stream>>>(feat, (const int*)d_ws + MLP_WORD_OFF, out, B);

  {
    int n4 = B*49/4;
    zero_kernel<<<(n4 + 255)/256, 256, 0, stream>>>((float4*)(out + 3*B), n4);
  }
}